// Round 19
// baseline (9502.005 us; speedup 1.0000x reference)
//
#include <hip/hip_runtime.h>
#include <stdint.h>

#define CDIM 256
#define NCLS 200
#define NSEL 128
#define SEQ  4096
#define RPB  16      // rows per score-block
#define CCH  32      // c-chunk staged in LDS (= one AVX2 einsum chunk)

// ---------------------------------------------------------------------------
// numpy dispatched f32 exp, AVX512_SKX path, FUSED quadrant (the actual
// simd_exp_FLOAT: quadrant = fma(x, log2e, 1.5*2^23) - 1.5*2^23, Cody-Waite
// 2-step (FMA), rational P5/Q2 (FMA), div, scalef). Inputs in [-88, 0].
// ---------------------------------------------------------------------------
__device__ __forceinline__ float np_expf(float x) {
    const float LOG2E = 1.442695040888963407359924681001892137f;
    const float MAGIC = 12582912.0f;                 // NPY_RINT_CVT_MAGICf
    const float CW_HI = -6.93145752e-1f;
    const float CW_LO = -1.42860677e-6f;

    float q = __fsub_rn(__fmaf_rn(x, LOG2E, MAGIC), MAGIC);   // fused quadrant

    float y = __fmaf_rn(q, CW_HI, x);
    y = __fmaf_rn(q, CW_LO, y);

    float num = __fmaf_rn(5.082762527590693718096e-04f, y,
                          6.757896990527504603057e-03f);
    num = __fmaf_rn(num, y, 5.114512081637298353406e-02f);
    num = __fmaf_rn(num, y, 2.473615434895520810817e-01f);
    num = __fmaf_rn(num, y, 7.257664613233124478488e-01f);
    num = __fmaf_rn(num, y, 9.999999999980870924916e-01f);

    float den = __fmaf_rn(2.159509375685829852307e-02f, y,
                          -2.742335390411667452936e-01f);
    den = __fmaf_rn(den, y, 1.0f);

    const float r = __fdiv_rn(num, den);
    return ldexpf(r, (int)q);
}

// ---------------------------------------------------------------------------
// numpy loops.c.src pairwise_sum base case (scalar 8-accumulator), m<=128;
// pairwise_sum(200) = block(96) + block(104), no tails.
// ---------------------------------------------------------------------------
__device__ __forceinline__ float np_pw_block(const float* a, int m) {
    float r8[8];
    #pragma unroll
    for (int k = 0; k < 8; ++k) r8[k] = a[k];
    int i = 8;
    const int mm = m - (m % 8);
    for (; i < mm; i += 8)
        #pragma unroll
        for (int k = 0; k < 8; ++k)
            r8[k] = __fadd_rn(r8[k], a[i + k]);
    float res =
        __fadd_rn(__fadd_rn(__fadd_rn(r8[0], r8[1]), __fadd_rn(r8[2], r8[3])),
                  __fadd_rn(__fadd_rn(r8[4], r8[5]), __fadd_rn(r8[6], r8[7])));
    for (; i < m; ++i) res = __fadd_rn(res, a[i]);
    return res;
}

// ---------------------------------------------------------------------------
// Kernel 1: NEW FAMILY -- np.einsum(optimize=False) compiled with AVX2+FMA
// baseline (internal source builds): sum_of_products_contig_outstride0_two
// with vstep=8: 8 lane accumulators (j = c%8); chunks of 32 ascending; within
// chunk, reversed sub-vector FUSED-FMA chain (ab3->ab2->ab1->vaccum);
// horizontal = AVX2 double-hadd + lo/hi: ((v0+v1)+(v2+v3))+((v4+v5)+(v6+v7)).
// softmax: m=max; e=np_expf(l-m); S=scalar8 pairwise 96+104; p=fl(emax/S).
// ---------------------------------------------------------------------------
__global__ __launch_bounds__(256) void score_replica_kernel(
    const float* __restrict__ x, const float* __restrict__ W,
    const float* __restrict__ bias, float* __restrict__ pmax)
{
    __shared__ float xs[RPB][CDIM];   // 16 KB
    __shared__ float wt[CCH][NCLS];   // 25.6 KB
    __shared__ float lg[RPB][NCLS];   // 12.8 KB

    const int tid = threadIdx.x;
    const long long row0 = (long long)blockIdx.x * RPB;

    for (int i = tid; i < RPB * CDIM; i += 256)
        xs[i >> 8][i & 255] = x[row0 * CDIM + i];

    // 16 rows x 200 classes = 3200 tasks, <=13 per thread; 8 AVX2 lanes each
    float acc[13][8];
    int   tr[13], tn[13];
    #pragma unroll
    for (int t = 0; t < 13; ++t) {
        const int task = t * 256 + tid;
        #pragma unroll
        for (int j = 0; j < 8; ++j) acc[t][j] = 0.0f;
        tr[t] = task / NCLS;
        tn[t] = task - tr[t] * NCLS;
    }

    for (int cc = 0; cc < CDIM; cc += CCH) {   // CCH=32 = exactly one chunk
        __syncthreads();
        for (int i = tid; i < CCH * NCLS; i += 256) {
            const int ci = i / NCLS;
            const int ni = i - ci * NCLS;
            wt[ci][ni] = W[(cc + ci) * NCLS + ni];
        }
        __syncthreads();
        #pragma unroll
        for (int t = 0; t < 13; ++t) {
            if (t * 256 + tid < RPB * NCLS) {
                const int r = tr[t], n = tn[t];
                // one 32-elem chunk: reversed sub-vector FUSED chain
                #pragma unroll
                for (int i = 3; i >= 0; --i) {
                    #pragma unroll
                    for (int j = 0; j < 8; ++j) {
                        const int u = 8 * i + j;
                        acc[t][j] = __fmaf_rn(xs[r][cc + u], wt[u][n], acc[t][j]);
                    }
                }
            }
        }
    }
    __syncthreads();
    #pragma unroll
    for (int t = 0; t < 13; ++t)
        if (t * 256 + tid < RPB * NCLS) {
            // AVX2 npyv_sum_f32: hadd,hadd,lo+hi
            const float h =
                __fadd_rn(__fadd_rn(__fadd_rn(acc[t][0], acc[t][1]),
                                    __fadd_rn(acc[t][2], acc[t][3])),
                          __fadd_rn(__fadd_rn(acc[t][4], acc[t][5]),
                                    __fadd_rn(acc[t][6], acc[t][7])));
            lg[tr[t]][tn[t]] = __fadd_rn(h, bias[tn[t]]);   // b==0: exact
        }
    __syncthreads();

    if (tid < RPB) {
        const int r = tid;
        float m = lg[r][0];
        for (int n = 1; n < NCLS; ++n) m = fmaxf(m, lg[r][n]);

        float emax = 0.0f;
        for (int n = 0; n < NCLS; ++n) {
            const float e = np_expf(__fsub_rn(lg[r][n], m));
            lg[r][n] = e;
            emax = fmaxf(emax, e);
        }

        const float s1 = np_pw_block(&lg[r][0], 96);
        const float s2 = np_pw_block(&lg[r][96], 104);
        const float S  = __fadd_rn(s1, s2);
        pmax[row0 + r] = __fdiv_rn(emax, S);
    }
}

// ---------------------------------------------------------------------------
// Kernel 2: per batch, sort 4096 packed keys desc (stable, smaller index
// first on ties), gather top-128 rows in rank order.
// ---------------------------------------------------------------------------
__global__ __launch_bounds__(256) void sort_gather_kernel(
    const float* __restrict__ pmax, const float* __restrict__ x,
    float* __restrict__ out)
{
    __shared__ uint64_t K[SEQ];   // 32 KB

    const int tid = threadIdx.x;
    const int b   = blockIdx.x;

    for (int i = tid; i < SEQ; i += 256) {
        const uint32_t pb = __float_as_uint(pmax[(long long)b * SEQ + i]);
        K[i] = ((uint64_t)pb << 12) | (uint64_t)(SEQ - 1 - i);
    }
    __syncthreads();

    for (int k = 2; k <= SEQ; k <<= 1) {
        for (int j = k >> 1; j > 0; j >>= 1) {
            for (int t = tid; t < SEQ / 2; t += 256) {
                const int i = ((t & ~(j - 1)) << 1) | (t & (j - 1));
                const int p = i | j;
                const bool desc = ((i & k) == 0);
                const uint64_t a = K[i], c = K[p];
                const bool sw = desc ? (a < c) : (a > c);
                if (sw) { K[i] = c; K[p] = a; }
            }
            __syncthreads();
        }
    }

    const float4* x4   = reinterpret_cast<const float4*>(x);
    float4*       out4 = reinterpret_cast<float4*>(out);
    for (int t = tid; t < NSEL * (CDIM / 4); t += 256) {
        const int jj = t >> 6;
        const int c4 = t & 63;
        const int idx = (SEQ - 1) - (int)(K[jj] & (uint64_t)(SEQ - 1));
        out4[((long long)b * NSEL + jj) * (CDIM / 4) + c4] =
            x4[((long long)b * SEQ + idx) * (CDIM / 4) + c4];
    }
}

extern "C" void kernel_launch(void* const* d_in, const int* in_sizes, int n_in,
                              void* d_out, int out_size, void* d_ws, size_t ws_size,
                              hipStream_t stream) {
    const float* x    = (const float*)d_in[0];
    const float* W    = (const float*)d_in[1];
    const float* bias = (const float*)d_in[2];
    float* out   = (float*)d_out;
    float* score = (float*)d_ws;                     // 131072 * 4 B = 512 KB

    const long long nrows = (long long)in_sizes[0] / CDIM;   // B*S
    const int B = out_size / (NSEL * CDIM);                  // 32

    score_replica_kernel<<<(int)(nrows / RPB), 256, 0, stream>>>(x, W, bias, score);
    sort_gather_kernel<<<B, 256, 0, stream>>>(score, x, out);
}

// Round 20
// 2042.612 us; speedup vs baseline: 4.6519x; 4.6519x over previous
//
#include <hip/hip_runtime.h>
#include <stdint.h>

#define CDIM 256
#define NCLS 200
#define NSEL 128
#define SEQ  4096
#define RPB  8       // rows per score-block (16 -> 8: kills VGPR spills)
#define CCH  32      // c-chunk staged in LDS (= one AVX2 einsum chunk)
#define TPT  7       // tasks per thread (ceil(8*200/256))

// ---------------------------------------------------------------------------
// numpy dispatched f32 exp, fused-quadrant rational path (VERIFIED bitwise
// vs harness reference in round 19 -- do not alter any operation).
// ---------------------------------------------------------------------------
__device__ __forceinline__ float np_expf(float x) {
    const float LOG2E = 1.442695040888963407359924681001892137f;
    const float MAGIC = 12582912.0f;
    const float CW_HI = -6.93145752e-1f;
    const float CW_LO = -1.42860677e-6f;

    float q = __fsub_rn(__fmaf_rn(x, LOG2E, MAGIC), MAGIC);

    float y = __fmaf_rn(q, CW_HI, x);
    y = __fmaf_rn(q, CW_LO, y);

    float num = __fmaf_rn(5.082762527590693718096e-04f, y,
                          6.757896990527504603057e-03f);
    num = __fmaf_rn(num, y, 5.114512081637298353406e-02f);
    num = __fmaf_rn(num, y, 2.473615434895520810817e-01f);
    num = __fmaf_rn(num, y, 7.257664613233124478488e-01f);
    num = __fmaf_rn(num, y, 9.999999999980870924916e-01f);

    float den = __fmaf_rn(2.159509375685829852307e-02f, y,
                          -2.742335390411667452936e-01f);
    den = __fmaf_rn(den, y, 1.0f);

    const float r = __fdiv_rn(num, den);
    return ldexpf(r, (int)q);
}

// ---------------------------------------------------------------------------
// Score kernel: SAME bitwise arithmetic as the round-19 PASS, restructured
// for performance only:
//  - RPB 16->8 (acc 104->56 VGPRs: no scratch spills; was 24 GB spill I/O)
//  - softmax parallelized with bitwise-safe transforms only:
//      max: fmax tree (associative/commutative, NaN-free -> bitwise equal)
//      exp: elementwise, parallel
//      sum: the 8 fixed accumulator chains distributed 1/thread; exact
//           combine tree ((r0+r1)+(r2+r3))+((r4+r5)+(r6+r7)) preserved
//      emax == 1.0f exactly (argmax class: np_expf(0) = 1.0f; all e <= 1)
// ---------------------------------------------------------------------------
__global__ __launch_bounds__(256) void score_kernel(
    const float* __restrict__ x, const float* __restrict__ W,
    const float* __restrict__ bias, float* __restrict__ scores)
{
    __shared__ float xs[RPB][CDIM];   // 8 KB
    __shared__ float wt[CCH][NCLS];   // 25.6 KB
    __shared__ float lg[RPB][NCLS];   // 6.4 KB (logits, then e-values)
    __shared__ float mx[RPB][32];     // 1 KB
    __shared__ float sp[RPB][16];     // 512 B (8 chain-accs x 2 blocks)
    __shared__ float mrow[RPB];

    const int tid = threadIdx.x;
    const long long row0 = (long long)blockIdx.x * RPB;

    for (int i = tid; i < RPB * CDIM; i += 256)
        xs[i >> 8][i & 255] = x[row0 * CDIM + i];

    // 8 rows x 200 classes = 1600 tasks, <=7 per thread; 8 AVX2 lanes each
    float acc[TPT][8];
    int   tr[TPT], tn[TPT];
    #pragma unroll
    for (int t = 0; t < TPT; ++t) {
        const int task = t * 256 + tid;
        #pragma unroll
        for (int j = 0; j < 8; ++j) acc[t][j] = 0.0f;
        tr[t] = task / NCLS;
        tn[t] = task - tr[t] * NCLS;
    }

    for (int cc = 0; cc < CDIM; cc += CCH) {   // chunks of 32, ascending
        __syncthreads();
        for (int i = tid; i < CCH * NCLS; i += 256) {
            const int ci = i / NCLS;
            const int ni = i - ci * NCLS;
            wt[ci][ni] = W[(cc + ci) * NCLS + ni];
        }
        __syncthreads();
        #pragma unroll
        for (int t = 0; t < TPT; ++t) {
            if (t * 256 + tid < RPB * NCLS) {
                const int r = tr[t], n = tn[t];
                // reversed sub-vector FUSED-FMA chain (ab3->ab2->ab1->vaccum)
                #pragma unroll
                for (int i = 3; i >= 0; --i) {
                    #pragma unroll
                    for (int j = 0; j < 8; ++j) {
                        const int u = 8 * i + j;
                        acc[t][j] = __fmaf_rn(xs[r][cc + u], wt[u][n], acc[t][j]);
                    }
                }
            }
        }
    }
    __syncthreads();
    #pragma unroll
    for (int t = 0; t < TPT; ++t)
        if (t * 256 + tid < RPB * NCLS) {
            // AVX2 npyv_sum_f32: hadd,hadd,lo+hi
            const float h =
                __fadd_rn(__fadd_rn(__fadd_rn(acc[t][0], acc[t][1]),
                                    __fadd_rn(acc[t][2], acc[t][3])),
                          __fadd_rn(__fadd_rn(acc[t][4], acc[t][5]),
                                    __fadd_rn(acc[t][6], acc[t][7])));
            lg[tr[t]][tn[t]] = __fadd_rn(h, bias[tn[t]]);   // b==0: exact
        }
    __syncthreads();

    // ---- row max: 8 rows x 32 slots, fmax tree (bitwise-safe) ----
    {
        const int r = tid >> 5, l = tid & 31;
        float mv = lg[r][l];
        for (int n = l + 32; n < NCLS; n += 32) mv = fmaxf(mv, lg[r][n]);
        mx[r][l] = mv;
    }
    __syncthreads();
    if (tid < RPB) {
        float mv = mx[tid][0];
        #pragma unroll
        for (int l = 1; l < 32; ++l) mv = fmaxf(mv, mx[tid][l]);
        mrow[tid] = mv;
    }
    __syncthreads();

    // ---- exp: elementwise, parallel ----
    for (int i = tid; i < RPB * NCLS; i += 256) {
        const int r = i / NCLS, n = i - (i / NCLS) * NCLS;
        lg[r][n] = np_expf(__fsub_rn(lg[r][n], mrow[r]));
    }
    __syncthreads();

    // ---- pairwise sum: 8 chains per row, exact association ----
    if (tid < RPB * 8) {
        const int r = tid >> 3, k = tid & 7;
        const float* a = lg[r];
        float c1 = a[k];                                   // block(96)
        for (int i = 8; i < 96; i += 8) c1 = __fadd_rn(c1, a[i + k]);
        const float* a2 = lg[r] + 96;                      // block(104)
        float c2 = a2[k];
        for (int i = 8; i < 104; i += 8) c2 = __fadd_rn(c2, a2[i + k]);
        sp[r][k] = c1;
        sp[r][8 + k] = c2;
    }
    __syncthreads();

    if (tid < RPB) {
        const float* p = sp[tid];
        const float s1 =
            __fadd_rn(__fadd_rn(__fadd_rn(p[0], p[1]), __fadd_rn(p[2], p[3])),
                      __fadd_rn(__fadd_rn(p[4], p[5]), __fadd_rn(p[6], p[7])));
        const float s2 =
            __fadd_rn(__fadd_rn(__fadd_rn(p[8], p[9]), __fadd_rn(p[10], p[11])),
                      __fadd_rn(__fadd_rn(p[12], p[13]), __fadd_rn(p[14], p[15])));
        const float S = __fadd_rn(s1, s2);
        scores[row0 + tid] = __fdiv_rn(1.0f, S);   // emax == 1.0f exactly
    }
}

// ---------------------------------------------------------------------------
// Kernel 2: per batch, sort 4096 packed keys desc (stable, smaller index
// first on ties), gather top-128 rows in rank order. (Unchanged from the
// round-19 PASS.)
// ---------------------------------------------------------------------------
__global__ __launch_bounds__(256) void sort_gather_kernel(
    const float* __restrict__ pmax, const float* __restrict__ x,
    float* __restrict__ out)
{
    __shared__ uint64_t K[SEQ];   // 32 KB

    const int tid = threadIdx.x;
    const int b   = blockIdx.x;

    for (int i = tid; i < SEQ; i += 256) {
        const uint32_t pb = __float_as_uint(pmax[(long long)b * SEQ + i]);
        K[i] = ((uint64_t)pb << 12) | (uint64_t)(SEQ - 1 - i);
    }
    __syncthreads();

    for (int k = 2; k <= SEQ; k <<= 1) {
        for (int j = k >> 1; j > 0; j >>= 1) {
            for (int t = tid; t < SEQ / 2; t += 256) {
                const int i = ((t & ~(j - 1)) << 1) | (t & (j - 1));
                const int p = i | j;
                const bool desc = ((i & k) == 0);
                const uint64_t a = K[i], c = K[p];
                const bool sw = desc ? (a < c) : (a > c);
                if (sw) { K[i] = c; K[p] = a; }
            }
            __syncthreads();
        }
    }

    const float4* x4   = reinterpret_cast<const float4*>(x);
    float4*       out4 = reinterpret_cast<float4*>(out);
    for (int t = tid; t < NSEL * (CDIM / 4); t += 256) {
        const int jj = t >> 6;
        const int c4 = t & 63;
        const int idx = (SEQ - 1) - (int)(K[jj] & (uint64_t)(SEQ - 1));
        out4[((long long)b * NSEL + jj) * (CDIM / 4) + c4] =
            x4[((long long)b * SEQ + idx) * (CDIM / 4) + c4];
    }
}

extern "C" void kernel_launch(void* const* d_in, const int* in_sizes, int n_in,
                              void* d_out, int out_size, void* d_ws, size_t ws_size,
                              hipStream_t stream) {
    const float* x    = (const float*)d_in[0];
    const float* W    = (const float*)d_in[1];
    const float* bias = (const float*)d_in[2];
    float* out   = (float*)d_out;
    float* score = (float*)d_ws;                     // 131072 * 4 B = 512 KB

    const long long nrows = (long long)in_sizes[0] / CDIM;   // B*S
    const int B = out_size / (NSEL * CDIM);                  // 32

    score_kernel<<<(int)(nrows / RPB), 256, 0, stream>>>(x, W, bias, score);
    sort_gather_kernel<<<B, 256, 0, stream>>>(score, x, out);
}

// Round 21
// 437.684 us; speedup vs baseline: 21.7098x; 4.6669x over previous
//
#include <hip/hip_runtime.h>
#include <stdint.h>

#define CDIM 256
#define NCLS 200
#define NSEL 128
#define SEQ  4096
#define RPB  16      // rows per score-block
#define CCH  32      // c-chunk staged in LDS (= one AVX2 einsum chunk)

// ---------------------------------------------------------------------------
// numpy dispatched f32 exp, fused-quadrant rational path (VERIFIED bitwise
// vs harness reference in rounds 19/20 -- do not alter any operation).
// ---------------------------------------------------------------------------
__device__ __forceinline__ float np_expf(float x) {
    const float LOG2E = 1.442695040888963407359924681001892137f;
    const float MAGIC = 12582912.0f;
    const float CW_HI = -6.93145752e-1f;
    const float CW_LO = -1.42860677e-6f;

    float q = __fsub_rn(__fmaf_rn(x, LOG2E, MAGIC), MAGIC);

    float y = __fmaf_rn(q, CW_HI, x);
    y = __fmaf_rn(q, CW_LO, y);

    float num = __fmaf_rn(5.082762527590693718096e-04f, y,
                          6.757896990527504603057e-03f);
    num = __fmaf_rn(num, y, 5.114512081637298353406e-02f);
    num = __fmaf_rn(num, y, 2.473615434895520810817e-01f);
    num = __fmaf_rn(num, y, 7.257664613233124478488e-01f);
    num = __fmaf_rn(num, y, 9.999999999980870924916e-01f);

    float den = __fmaf_rn(2.159509375685829852307e-02f, y,
                          -2.742335390411667452936e-01f);
    den = __fmaf_rn(den, y, 1.0f);

    const float r = __fdiv_rn(num, den);
    return ldexpf(r, (int)q);
}

// ---------------------------------------------------------------------------
// Score kernel: bitwise-identical arithmetic to the round-19/20 PASS,
// restructured: 4-row x 4-class register tile per thread, float4 LDS reads.
//  - per (r,n) output, lane-j chains run chunks ascending, i = 3..0 (exact)
//  - hadd combine ((a0+a1)+(a2+a3))+((a4+a5)+(a6+a7)), + bias
//  - softmax: fmax tree (assoc-safe), np_expf, 8-chain pairwise 96+104,
//    S = s1+s2, p = 1/S (emax == 1.0f exactly, validated r20)
// ---------------------------------------------------------------------------
__global__ __launch_bounds__(256) void score_kernel(
    const float* __restrict__ x, const float* __restrict__ W,
    const float* __restrict__ bias, float* __restrict__ scores)
{
    __shared__ __align__(16) float xs[RPB * CDIM];    // 16 KB
    __shared__ __align__(16) float wtb[CCH * NCLS];   // 25.6 KB (aliased as lg after K-loop)
    __shared__ float mx[RPB][16];
    __shared__ float sp[RPB][16];
    __shared__ float mrow[RPB];

    const int tid = threadIdx.x;
    const long long row0 = (long long)blockIdx.x * RPB;

    // stage x tile (float4, coalesced)
    {
        const float4* xg = reinterpret_cast<const float4*>(x + row0 * CDIM);
        float4* xs4 = reinterpret_cast<float4*>(xs);
        for (int i = tid; i < RPB * CDIM / 4; i += 256) xs4[i] = xg[i];
    }

    const int rg = tid / 50;          // row group (0..3) for tid<200
    const int q  = tid - rg * 50;     // class quad (0..49)
    const bool active = (tid < 200);

    float acc[4][4][8];               // [row][class][chain-lane] = 128 VGPRs
    #pragma unroll
    for (int r = 0; r < 4; ++r)
        #pragma unroll
        for (int k = 0; k < 4; ++k)
            #pragma unroll
            for (int j = 0; j < 8; ++j) acc[r][k][j] = 0.0f;

    for (int cc = 0; cc < CDIM; cc += CCH) {   // chunks of 32, ascending
        __syncthreads();
        {   // stage W chunk (float4, coalesced; global source contiguous)
            const float4* wg = reinterpret_cast<const float4*>(W + cc * NCLS);
            float4* wt4 = reinterpret_cast<float4*>(wtb);
            for (int i = tid; i < CCH * NCLS / 4; i += 256) wt4[i] = wg[i];
        }
        __syncthreads();

        if (active) {
            #pragma unroll
            for (int i = 3; i >= 0; --i) {     // reversed sub-vectors (exact)
                float4 xq0[4], xq1[4];
                #pragma unroll
                for (int r = 0; r < 4; ++r) {
                    const float* xrow = &xs[(rg * 4 + r) * CDIM + cc + 8 * i];
                    xq0[r] = *reinterpret_cast<const float4*>(xrow);
                    xq1[r] = *reinterpret_cast<const float4*>(xrow + 4);
                }
                #pragma unroll
                for (int j = 0; j < 8; ++j) {
                    const float4 wv = *reinterpret_cast<const float4*>(
                        &wtb[(8 * i + j) * NCLS + 4 * q]);
                    #pragma unroll
                    for (int r = 0; r < 4; ++r) {
                        const float xv = (j < 4)
                            ? reinterpret_cast<const float*>(&xq0[r])[j]
                            : reinterpret_cast<const float*>(&xq1[r])[j - 4];
                        acc[r][0][j] = __fmaf_rn(xv, wv.x, acc[r][0][j]);
                        acc[r][1][j] = __fmaf_rn(xv, wv.y, acc[r][1][j]);
                        acc[r][2][j] = __fmaf_rn(xv, wv.z, acc[r][2][j]);
                        acc[r][3][j] = __fmaf_rn(xv, wv.w, acc[r][3][j]);
                    }
                }
            }
        }
    }
    __syncthreads();                  // all wtb reads done; reuse as lg
    float* lg = wtb;                  // lg[RPB][NCLS], 12.8 KB of the 25.6

    if (active) {
        const float4 bq = reinterpret_cast<const float4*>(bias)[q];
        const float bv[4] = { bq.x, bq.y, bq.z, bq.w };
        #pragma unroll
        for (int r = 0; r < 4; ++r) {
            float h[4];
            #pragma unroll
            for (int k = 0; k < 4; ++k) {
                const float* a = acc[r][k];
                h[k] = __fadd_rn(
                    __fadd_rn(__fadd_rn(a[0], a[1]), __fadd_rn(a[2], a[3])),
                    __fadd_rn(__fadd_rn(a[4], a[5]), __fadd_rn(a[6], a[7])));
                h[k] = __fadd_rn(h[k], bv[k]);          // b==0: exact no-op
            }
            *reinterpret_cast<float4*>(&lg[(rg * 4 + r) * NCLS + 4 * q]) =
                make_float4(h[0], h[1], h[2], h[3]);
        }
    }
    __syncthreads();

    // ---- row max: 16 rows x 16 slots, fmax tree (bitwise-safe) ----
    {
        const int r = tid >> 4, l = tid & 15;
        float mv = lg[r * NCLS + l];
        for (int n = l + 16; n < NCLS; n += 16) mv = fmaxf(mv, lg[r * NCLS + n]);
        mx[r][l] = mv;
    }
    __syncthreads();
    if (tid < RPB) {
        float mv = mx[tid][0];
        #pragma unroll
        for (int l = 1; l < 16; ++l) mv = fmaxf(mv, mx[tid][l]);
        mrow[tid] = mv;
    }
    __syncthreads();

    // ---- exp: elementwise, parallel ----
    for (int i = tid; i < RPB * NCLS; i += 256) {
        const int r = i / NCLS;
        lg[i] = np_expf(__fsub_rn(lg[i], mrow[r]));
    }
    __syncthreads();

    // ---- pairwise sum: 8 chains x 2 blocks x 16 rows = 256 threads ----
    {
        const int r = tid >> 4, sub = tid & 15;
        const int k = sub & 7, blk = sub >> 3;
        const float* a = &lg[r * NCLS + (blk ? 96 : 0)];
        const int len = blk ? 104 : 96;
        float c = a[k];
        for (int i = 8; i < len; i += 8) c = __fadd_rn(c, a[i + k]);
        sp[r][blk * 8 + k] = c;
    }
    __syncthreads();

    if (tid < RPB) {
        const float* p = sp[tid];
        const float s1 =
            __fadd_rn(__fadd_rn(__fadd_rn(p[0], p[1]), __fadd_rn(p[2], p[3])),
                      __fadd_rn(__fadd_rn(p[4], p[5]), __fadd_rn(p[6], p[7])));
        const float s2 =
            __fadd_rn(__fadd_rn(__fadd_rn(p[8], p[9]), __fadd_rn(p[10], p[11])),
                      __fadd_rn(__fadd_rn(p[12], p[13]), __fadd_rn(p[14], p[15])));
        const float S = __fadd_rn(s1, s2);
        scores[row0 + tid] = __fdiv_rn(1.0f, S);   // emax == 1.0f exactly
    }
}

// ---------------------------------------------------------------------------
// Kernel 2: per batch, sort 4096 packed keys desc (stable, smaller index
// first on ties), gather top-128 rows in rank order. (Unchanged from PASS.)
// ---------------------------------------------------------------------------
__global__ __launch_bounds__(256) void sort_gather_kernel(
    const float* __restrict__ pmax, const float* __restrict__ x,
    float* __restrict__ out)
{
    __shared__ uint64_t K[SEQ];   // 32 KB

    const int tid = threadIdx.x;
    const int b   = blockIdx.x;

    for (int i = tid; i < SEQ; i += 256) {
        const uint32_t pb = __float_as_uint(pmax[(long long)b * SEQ + i]);
        K[i] = ((uint64_t)pb << 12) | (uint64_t)(SEQ - 1 - i);
    }
    __syncthreads();

    for (int k = 2; k <= SEQ; k <<= 1) {
        for (int j = k >> 1; j > 0; j >>= 1) {
            for (int t = tid; t < SEQ / 2; t += 256) {
                const int i = ((t & ~(j - 1)) << 1) | (t & (j - 1));
                const int p = i | j;
                const bool desc = ((i & k) == 0);
                const uint64_t a = K[i], c = K[p];
                const bool sw = desc ? (a < c) : (a > c);
                if (sw) { K[i] = c; K[p] = a; }
            }
            __syncthreads();
        }
    }

    const float4* x4   = reinterpret_cast<const float4*>(x);
    float4*       out4 = reinterpret_cast<float4*>(out);
    for (int t = tid; t < NSEL * (CDIM / 4); t += 256) {
        const int jj = t >> 6;
        const int c4 = t & 63;
        const int idx = (SEQ - 1) - (int)(K[jj] & (uint64_t)(SEQ - 1));
        out4[((long long)b * NSEL + jj) * (CDIM / 4) + c4] =
            x4[((long long)b * SEQ + idx) * (CDIM / 4) + c4];
    }
}

extern "C" void kernel_launch(void* const* d_in, const int* in_sizes, int n_in,
                              void* d_out, int out_size, void* d_ws, size_t ws_size,
                              hipStream_t stream) {
    const float* x    = (const float*)d_in[0];
    const float* W    = (const float*)d_in[1];
    const float* bias = (const float*)d_in[2];
    float* out   = (float*)d_out;
    float* score = (float*)d_ws;                     // 131072 * 4 B = 512 KB

    const long long nrows = (long long)in_sizes[0] / CDIM;   // B*S
    const int B = out_size / (NSEL * CDIM);                  // 32

    score_kernel<<<(int)(nrows / RPB), 256, 0, stream>>>(x, W, bias, score);
    sort_gather_kernel<<<B, 256, 0, stream>>>(score, x, out);
}